// Round 1
// baseline (573.025 us; speedup 1.0000x reference)
//
#include <hip/hip_runtime.h>
#include <hip/hip_bf16.h>

// ---------------------------------------------------------------------------
// Stage 1-3: fused-bias(+ReLU) tiled fp32 GEMM  C[M,N] = act(A[M,K] @ W[K,N] + b)
// BM=64 rows/block, 256 threads (tx=32 col-threads x ty=8 row-threads),
// micro-tile TM=8 x TN=NP/32. KC=20 divides both K=200 and K=100.
// A-tile stored transposed (At[k][r], padded stride 68) so the 8-row fragment
// is two ds_read_b128; W-tile zero-padded to NP cols so compute is unguarded.
// ---------------------------------------------------------------------------
template <int K, int N, int NP, bool RELU>
__launch_bounds__(256)
__global__ void mlp_gemm(const float* __restrict__ A, const float* __restrict__ W,
                         const float* __restrict__ bias, float* __restrict__ C) {
  constexpr int BM = 64;
  constexpr int KC = 20;          // divides 200 and 100
  constexpr int TM = 8;
  constexpr int TN = NP / 32;     // 4 (N=100) or 8 (N=200)
  constexpr int BMP = BM + 4;     // 68: pad (mult of 4 -> 16B-aligned rows, breaks conflicts)

  __shared__ float At[KC * BMP];
  __shared__ float Ws[KC * NP];

  const int t = threadIdx.x;
  const int tx = t & 31;
  const int ty = t >> 5;
  const int rowBase = blockIdx.x * BM;

  float acc[TM][TN];
#pragma unroll
  for (int i = 0; i < TM; i++)
#pragma unroll
    for (int j = 0; j < TN; j++) acc[i][j] = 0.0f;

  for (int kc = 0; kc < K; kc += KC) {
    // A tile -> LDS, transposed: At[k][r]
#pragma unroll
    for (int i = t; i < BM * KC; i += 256) {
      int r = i / KC;
      int k = i - r * KC;
      At[k * BMP + r] = A[(rowBase + r) * K + kc + k];
    }
    // W tile -> LDS, zero-padded cols: Ws[k][c]
#pragma unroll
    for (int i = t; i < KC * NP; i += 256) {
      int k = i / NP;
      int c = i - k * NP;
      Ws[i] = (c < N) ? W[(kc + k) * N + c] : 0.0f;
    }
    __syncthreads();

#pragma unroll
    for (int k = 0; k < KC; k++) {
      float a[TM], b[TN];
      *(float4*)&a[0] = *(const float4*)&At[k * BMP + ty * TM];
      *(float4*)&a[4] = *(const float4*)&At[k * BMP + ty * TM + 4];
#pragma unroll
      for (int j = 0; j < TN; j += 4)
        *(float4*)&b[j] = *(const float4*)&Ws[k * NP + tx * TN + j];
#pragma unroll
      for (int i = 0; i < TM; i++)
#pragma unroll
        for (int j = 0; j < TN; j++) acc[i][j] += a[i] * b[j];
    }
    __syncthreads();
  }

  const int c0 = tx * TN;
  if (c0 < N) {  // for both configs a thread's cols are all-in or all-out
#pragma unroll
    for (int i = 0; i < TM; i++) {
      const int r = rowBase + ty * TM + i;
#pragma unroll
      for (int j = 0; j < TN; j += 4) {
        float4 v;
        v.x = acc[i][j + 0] + bias[c0 + j + 0];
        v.y = acc[i][j + 1] + bias[c0 + j + 1];
        v.z = acc[i][j + 2] + bias[c0 + j + 2];
        v.w = acc[i][j + 3] + bias[c0 + j + 3];
        if (RELU) {
          v.x = fmaxf(v.x, 0.0f);
          v.y = fmaxf(v.y, 0.0f);
          v.z = fmaxf(v.z, 0.0f);
          v.w = fmaxf(v.w, 0.0f);
        }
        *(float4*)&C[r * N + c0 + j] = v;
      }
    }
  }
}

// ---------------------------------------------------------------------------
// Stage 4: SampleConcrete + masked head.
// One wave (64 lanes) per row b. Lane l owns d = l, l+64, l+128, (l+192 if l<8).
// For each of K=10 gumbel draws: softmax over d (shuffle reductions), running
// max over k. Then samples write, xs = x*samples, 2-class softmax head.
// Memory-bound on uniform (262 MB).
// ---------------------------------------------------------------------------
__launch_bounds__(256)
__global__ void concrete_kernel(const float* __restrict__ x,
                                const float* __restrict__ uniform,
                                const float* __restrict__ logits,
                                const float* __restrict__ wo,
                                const float* __restrict__ bo,
                                float* __restrict__ out, int B) {
  const int lane = threadIdx.x & 63;
  const int wave = threadIdx.x >> 6;
  const int b = blockIdx.x * 4 + wave;
  if (b >= B) return;

  constexpr float EPS = 1.1920929e-07f;  // float32 eps
  constexpr int D = 200;

  // i=0,1,2 always valid (lane+128 <= 191 < 200); i=3 valid only for lane<8
  float lg[4], xv[4], smax[4];
#pragma unroll
  for (int i = 0; i < 4; i++) {
    const int d = lane + 64 * i;
    const bool v = (d < D);
    lg[i] = v ? logits[b * D + d] : 0.0f;
    xv[i] = v ? x[b * D + d] : 0.0f;
    smax[i] = 0.0f;
  }

  const float* __restrict__ urow = uniform + (size_t)b * 10 * D;
#pragma unroll 1
  for (int k = 0; k < 10; k++) {
    const float* __restrict__ u = urow + k * D;
    float noisy[4];
    float mloc = -1e30f;
#pragma unroll
    for (int i = 0; i < 4; i++) {
      const int d = lane + 64 * i;
      if (d < D) {
        float uu = u[d];
        uu = fminf(fmaxf(uu, EPS), 1.0f);
        const float g = -__logf(-__logf(uu));  // gumbel
        noisy[i] = (g + lg[i]) * 2.0f;         // / tau0 (=0.5)
        mloc = fmaxf(mloc, noisy[i]);
      } else {
        noisy[i] = -1e30f;
      }
    }
    // wave-wide max
#pragma unroll
    for (int off = 32; off > 0; off >>= 1)
      mloc = fmaxf(mloc, __shfl_xor(mloc, off, 64));

    float e[4];
    float ssum = 0.0f;
#pragma unroll
    for (int i = 0; i < 4; i++) {
      e[i] = (lane + 64 * i < D) ? __expf(noisy[i] - mloc) : 0.0f;
      ssum += e[i];
    }
#pragma unroll
    for (int off = 32; off > 0; off >>= 1)
      ssum += __shfl_xor(ssum, off, 64);

    const float inv = 1.0f / ssum;
#pragma unroll
    for (int i = 0; i < 4; i++) smax[i] = fmaxf(smax[i], e[i] * inv);
  }

  // samples out + head partials
  float p0 = 0.0f, p1 = 0.0f;
  const int samplesBase = B * 2;
#pragma unroll
  for (int i = 0; i < 4; i++) {
    const int d = lane + 64 * i;
    if (d < D) {
      const float s = smax[i];
      out[samplesBase + b * D + d] = s;
      const float xs = xv[i] * s;
      p0 += xs * wo[d * 2 + 0];
      p1 += xs * wo[d * 2 + 1];
    }
  }
#pragma unroll
  for (int off = 32; off > 0; off >>= 1) {
    p0 += __shfl_xor(p0, off, 64);
    p1 += __shfl_xor(p1, off, 64);
  }
  if (lane == 0) {
    const float z0 = p0 + bo[0];
    const float z1 = p1 + bo[1];
    const float m = fmaxf(z0, z1);
    const float e0 = __expf(z0 - m);
    const float e1 = __expf(z1 - m);
    const float s = e0 + e1;
    out[b * 2 + 0] = e0 / s;
    out[b * 2 + 1] = e1 / s;
  }
}

extern "C" void kernel_launch(void* const* d_in, const int* in_sizes, int n_in,
                              void* d_out, int out_size, void* d_ws, size_t ws_size,
                              hipStream_t stream) {
  const float* x  = (const float*)d_in[0];
  const float* un = (const float*)d_in[1];
  const float* w1 = (const float*)d_in[2];
  const float* b1 = (const float*)d_in[3];
  const float* w2 = (const float*)d_in[4];
  const float* b2 = (const float*)d_in[5];
  const float* wl = (const float*)d_in[6];
  const float* bl = (const float*)d_in[7];
  const float* wo = (const float*)d_in[8];
  const float* bo = (const float*)d_in[9];
  float* out = (float*)d_out;

  const int B = in_sizes[0] / 200;  // 32768

  // Workspace layout (39.3 MB total):
  //   h2     @ 0              (B*100 fp32, 13.1 MB)
  //   h1     @ B*100          (B*100 fp32, 13.1 MB)
  //   logits @ B*100          (B*200 fp32, 26.2 MB) -- overlays h1, which is
  //                            dead once stage-2 has consumed it; stage-3
  //                            reads only h2 and writes logits. Disjoint.
  float* h2 = (float*)d_ws;
  float* h1 = h2 + (size_t)B * 100;
  float* logits = h1;

  // Stage 1: h1 = relu(x @ w1 + b1)        (K=200, N=100)
  mlp_gemm<200, 100, 128, true><<<B / 64, 256, 0, stream>>>(x, w1, b1, h1);
  // Stage 2: h2 = relu(h1 @ w2 + b2)       (K=100, N=100)
  mlp_gemm<100, 100, 128, true><<<B / 64, 256, 0, stream>>>(h1, w2, b2, h2);
  // Stage 3: logits = h2 @ wl + bl         (K=100, N=200)
  mlp_gemm<100, 200, 256, false><<<B / 64, 256, 0, stream>>>(h2, wl, bl, logits);
  // Stage 4: concrete sampling + head
  concrete_kernel<<<B / 4, 256, 0, stream>>>(x, un, logits, wo, bo, out, B);
}

// Round 2
// 566.199 us; speedup vs baseline: 1.0121x; 1.0121x over previous
//
#include <hip/hip_runtime.h>
#include <hip/hip_bf16.h>

// ---------------------------------------------------------------------------
// Kernel A: fused dense1+dense2.  h2 = relu(relu(x@w1+b1)@w2+b2)
// 256 threads, BM=64 rows/block. tx=32 col-threads x ty=8 row-threads,
// micro-tile 8x4. h1 kept in LDS (transposed [k][r]) between the two GEMMs.
// ---------------------------------------------------------------------------
__launch_bounds__(256)
__global__ void fused_mlp12(const float* __restrict__ x,
                            const float* __restrict__ w1, const float* __restrict__ b1,
                            const float* __restrict__ w2, const float* __restrict__ b2,
                            float* __restrict__ h2out) {
  constexpr int BM = 64, KC = 20, BMP = 68;  // BMP*4B = 272B, 16B-aligned rows
  __shared__ float At[KC * BMP];    // 5.4 KB  staging: x^T chunk [k][r]
  __shared__ float Ws[KC * 128];    // 10.2 KB staging: weight chunk [k][c], cols padded
  __shared__ float h1T[100 * BMP];  // 27.2 KB h1 transposed [k][r]

  const int t = threadIdx.x;
  const int tx = t & 31;
  const int ty = t >> 5;
  const int rowBase = blockIdx.x * BM;

  float acc[8][4];
#pragma unroll
  for (int i = 0; i < 8; i++)
#pragma unroll
    for (int j = 0; j < 4; j++) acc[i][j] = 0.0f;

  // ---- GEMM 1: x(64x200) @ w1(200x100) ----
  for (int kc = 0; kc < 200; kc += KC) {
#pragma unroll
    for (int i = t; i < BM * KC; i += 256) {
      int r = i / KC, k = i - r * KC;
      At[k * BMP + r] = x[(rowBase + r) * 200 + kc + k];
    }
#pragma unroll
    for (int i = t; i < KC * 128; i += 256) {
      int k = i >> 7, c = i & 127;
      Ws[i] = (c < 100) ? w1[(kc + k) * 100 + c] : 0.0f;
    }
    __syncthreads();
#pragma unroll
    for (int k = 0; k < KC; k++) {
      float a[8], b[4];
      *(float4*)&a[0] = *(const float4*)&At[k * BMP + ty * 8];
      *(float4*)&a[4] = *(const float4*)&At[k * BMP + ty * 8 + 4];
      *(float4*)&b[0] = *(const float4*)&Ws[k * 128 + tx * 4];
#pragma unroll
      for (int i = 0; i < 8; i++)
#pragma unroll
        for (int j = 0; j < 4; j++) acc[i][j] += a[i] * b[j];
    }
    __syncthreads();
  }

  // h1 (bias+relu) -> LDS transposed [k][r]
  if (tx < 25) {
#pragma unroll
    for (int i = 0; i < 8; i++) {
      const int r = ty * 8 + i;
#pragma unroll
      for (int j = 0; j < 4; j++) {
        const int c = tx * 4 + j;
        h1T[c * BMP + r] = fmaxf(acc[i][j] + b1[c], 0.0f);
      }
    }
  }
  __syncthreads();

  // ---- GEMM 2: h1(64x100) @ w2(100x100) ----
#pragma unroll
  for (int i = 0; i < 8; i++)
#pragma unroll
    for (int j = 0; j < 4; j++) acc[i][j] = 0.0f;

  for (int kc = 0; kc < 100; kc += KC) {
#pragma unroll
    for (int i = t; i < KC * 128; i += 256) {
      int k = i >> 7, c = i & 127;
      Ws[i] = (c < 100) ? w2[(kc + k) * 100 + c] : 0.0f;
    }
    __syncthreads();
#pragma unroll
    for (int k = 0; k < KC; k++) {
      float a[8], b[4];
      *(float4*)&a[0] = *(const float4*)&h1T[(kc + k) * BMP + ty * 8];
      *(float4*)&a[4] = *(const float4*)&h1T[(kc + k) * BMP + ty * 8 + 4];
      *(float4*)&b[0] = *(const float4*)&Ws[k * 128 + tx * 4];
#pragma unroll
      for (int i = 0; i < 8; i++)
#pragma unroll
        for (int j = 0; j < 4; j++) acc[i][j] += a[i] * b[j];
    }
    __syncthreads();
  }

  if (tx < 25) {
#pragma unroll
    for (int i = 0; i < 8; i++) {
      const int r = rowBase + ty * 8 + i;
      float4 v;
      v.x = fmaxf(acc[i][0] + b2[tx * 4 + 0], 0.0f);
      v.y = fmaxf(acc[i][1] + b2[tx * 4 + 1], 0.0f);
      v.z = fmaxf(acc[i][2] + b2[tx * 4 + 2], 0.0f);
      v.w = fmaxf(acc[i][3] + b2[tx * 4 + 3], 0.0f);
      *(float4*)&h2out[r * 100 + tx * 4] = v;
    }
  }
}

// ---------------------------------------------------------------------------
// Kernel B: fused logits-GEMM + SampleConcrete + head.
// 512 threads, BM=64 rows/block. Phase 1: logits tile (64x200) -> LDS
// (tx=32 x ty=16, micro-tile 4x8, wl staged in KC=20 chunks).
// Phase 2: 8 waves x 8 rows each; all 10 gumbel samples' uniform loads
// batched into registers (40 dw/lane in flight) before the softmax chain.
// ---------------------------------------------------------------------------
__launch_bounds__(512, 4)
__global__ void fused_logits_concrete(const float* __restrict__ x,
                                      const float* __restrict__ uniform,
                                      const float* __restrict__ h2,
                                      const float* __restrict__ wl, const float* __restrict__ bl,
                                      const float* __restrict__ wo, const float* __restrict__ bo,
                                      float* __restrict__ out, int B) {
  constexpr int BM = 64, KC = 20, BMP = 68;
  constexpr float EPS = 1.1920929e-07f;
  __shared__ float At[KC * BMP];   // 5.4 KB  h2^T chunk [k][r]
  __shared__ float Ws[KC * 256];   // 20.5 KB wl chunk [k][c] padded 200->256
  __shared__ float lg[BM * 200];   // 51.2 KB logits tile [r][c]

  const int t = threadIdx.x;
  const int rowBase = blockIdx.x * BM;

  // ---- Phase 1: logits = h2(64x100) @ wl(100x200) + bl ----
  {
    const int tx = t & 31;
    const int ty = t >> 5;  // 0..15, rows ty*4..+3
    float acc[4][8];
#pragma unroll
    for (int i = 0; i < 4; i++)
#pragma unroll
      for (int j = 0; j < 8; j++) acc[i][j] = 0.0f;

    for (int kc = 0; kc < 100; kc += KC) {
      for (int i = t; i < BM * KC; i += 512) {
        int r = i / KC, k = i - r * KC;
        At[k * BMP + r] = h2[(rowBase + r) * 100 + kc + k];
      }
#pragma unroll
      for (int i = t; i < KC * 256; i += 512) {
        int k = i >> 8, c = i & 255;
        Ws[i] = (c < 200) ? wl[(kc + k) * 200 + c] : 0.0f;
      }
      __syncthreads();
#pragma unroll
      for (int k = 0; k < KC; k++) {
        float a[4], b[8];
        *(float4*)&a[0] = *(const float4*)&At[k * BMP + ty * 4];
        *(float4*)&b[0] = *(const float4*)&Ws[k * 256 + tx * 8];
        *(float4*)&b[4] = *(const float4*)&Ws[k * 256 + tx * 8 + 4];
#pragma unroll
        for (int i = 0; i < 4; i++)
#pragma unroll
          for (int j = 0; j < 8; j++) acc[i][j] += a[i] * b[j];
      }
      __syncthreads();
    }

    if (tx < 25) {
#pragma unroll
      for (int i = 0; i < 4; i++) {
        const int r = ty * 4 + i;
        float4 v0, v1;
        v0.x = acc[i][0] + bl[tx * 8 + 0];
        v0.y = acc[i][1] + bl[tx * 8 + 1];
        v0.z = acc[i][2] + bl[tx * 8 + 2];
        v0.w = acc[i][3] + bl[tx * 8 + 3];
        v1.x = acc[i][4] + bl[tx * 8 + 4];
        v1.y = acc[i][5] + bl[tx * 8 + 5];
        v1.z = acc[i][6] + bl[tx * 8 + 6];
        v1.w = acc[i][7] + bl[tx * 8 + 7];
        *(float4*)&lg[r * 200 + tx * 8] = v0;
        *(float4*)&lg[r * 200 + tx * 8 + 4] = v1;
      }
    }
    __syncthreads();
  }

  // ---- Phase 2: SampleConcrete + head; one wave per row, 8 rows/wave ----
  const int lane = t & 63;
  const int wave = t >> 6;  // 0..7
  const int samplesBase = B * 2;

#pragma unroll 1
  for (int rr = 0; rr < 8; rr++) {
    const int r = wave * 8 + rr;
    const int b = rowBase + r;

    float lgv[4], xv[4], smax[4];
#pragma unroll
    for (int i = 0; i < 4; i++) {
      const int d = lane + 64 * i;
      const bool v = (d < 200);
      lgv[i] = v ? lg[r * 200 + d] : 0.0f;
      xv[i] = v ? x[(size_t)b * 200 + d] : 0.0f;
      smax[i] = 0.0f;
    }

    // batch all 10 samples' uniform loads
    const float* __restrict__ u = uniform + (size_t)b * 2000;
    float uu[10][4];
#pragma unroll
    for (int k = 0; k < 10; k++)
#pragma unroll
      for (int i = 0; i < 4; i++) {
        const int d = lane + 64 * i;
        uu[k][i] = (d < 200) ? u[k * 200 + d] : 0.5f;
      }

#pragma unroll
    for (int k = 0; k < 10; k++) {
      float noisy[4];
      float mloc = -1e30f;
#pragma unroll
      for (int i = 0; i < 4; i++) {
        if (lane + 64 * i < 200) {
          float uc = fminf(fmaxf(uu[k][i], EPS), 1.0f);
          const float g = -__logf(-__logf(uc));
          noisy[i] = (g + lgv[i]) * 2.0f;  // / tau0 (=0.5)
          mloc = fmaxf(mloc, noisy[i]);
        } else {
          noisy[i] = -1e30f;
        }
      }
#pragma unroll
      for (int off = 32; off > 0; off >>= 1)
        mloc = fmaxf(mloc, __shfl_xor(mloc, off, 64));

      float e[4], ssum = 0.0f;
#pragma unroll
      for (int i = 0; i < 4; i++) {
        e[i] = (lane + 64 * i < 200) ? __expf(noisy[i] - mloc) : 0.0f;
        ssum += e[i];
      }
#pragma unroll
      for (int off = 32; off > 0; off >>= 1)
        ssum += __shfl_xor(ssum, off, 64);

      const float inv = 1.0f / ssum;
#pragma unroll
      for (int i = 0; i < 4; i++) smax[i] = fmaxf(smax[i], e[i] * inv);
    }

    float p0 = 0.0f, p1 = 0.0f;
#pragma unroll
    for (int i = 0; i < 4; i++) {
      const int d = lane + 64 * i;
      if (d < 200) {
        const float s = smax[i];
        out[samplesBase + (size_t)b * 200 + d] = s;
        const float xs = xv[i] * s;
        p0 += xs * wo[d * 2 + 0];
        p1 += xs * wo[d * 2 + 1];
      }
    }
#pragma unroll
    for (int off = 32; off > 0; off >>= 1) {
      p0 += __shfl_xor(p0, off, 64);
      p1 += __shfl_xor(p1, off, 64);
    }
    if (lane == 0) {
      const float z0 = p0 + bo[0];
      const float z1 = p1 + bo[1];
      const float m = fmaxf(z0, z1);
      const float e0 = __expf(z0 - m);
      const float e1 = __expf(z1 - m);
      out[b * 2 + 0] = e0 / (e0 + e1);
      out[b * 2 + 1] = e1 / (e0 + e1);
    }
  }
}

extern "C" void kernel_launch(void* const* d_in, const int* in_sizes, int n_in,
                              void* d_out, int out_size, void* d_ws, size_t ws_size,
                              hipStream_t stream) {
  const float* x  = (const float*)d_in[0];
  const float* un = (const float*)d_in[1];
  const float* w1 = (const float*)d_in[2];
  const float* b1 = (const float*)d_in[3];
  const float* w2 = (const float*)d_in[4];
  const float* b2 = (const float*)d_in[5];
  const float* wl = (const float*)d_in[6];
  const float* bl = (const float*)d_in[7];
  const float* wo = (const float*)d_in[8];
  const float* bo = (const float*)d_in[9];
  float* out = (float*)d_out;

  const int B = in_sizes[0] / 200;  // 32768
  float* h2 = (float*)d_ws;         // B*100 fp32 = 13.1 MB

  fused_mlp12<<<B / 64, 256, 0, stream>>>(x, w1, b1, w2, b2, h2);
  fused_logits_concrete<<<B / 64, 512, 0, stream>>>(x, un, h2, wl, bl, wo, bo, out, B);
}